// Round 10
// baseline (284.057 us; speedup 1.0000x reference)
//
#include <hip/hip_runtime.h>
#include <hip/hip_bf16.h>
#include <math.h>

#define NN 50000
#define NNP 50048          // padded rows
#define NE 1600000
#define FIN 9
#define DD 128
#define NG 64
#define PSEG 16
#define LN_EPS 1e-5f

// binning: 196 buckets x 256 dst nodes, fixed regions
#define NB 196
#define BSHIFT 8
#define CH 8192            // edges per bscatter block
#define MAXBE 12288        // raw entries reserved per bucket (mean 8163, +45 sigma)
#define MAXPB 20480        // padded csr entries reserved per bucket

typedef __attribute__((ext_vector_type(8))) short bf16x8;
typedef __attribute__((ext_vector_type(4))) float f32x4;
typedef __attribute__((ext_vector_type(2))) float f32x2;

static __device__ __forceinline__ unsigned short f2b(float f) {
  __hip_bfloat16 h = __float2bfloat16(f);
  return __builtin_bit_cast(unsigned short, h);
}
static __device__ __forceinline__ unsigned char f2e4m3(float f) {
  int r = __builtin_amdgcn_cvt_pk_fp8_f32(f, f, 0, false);
  return (unsigned char)(r & 0xFF);
}

// ---------------------------------------------------------------- prep: Wt x3, bcur, gstart, pads
__global__ __launch_bounds__(256) void k_prep(const float* __restrict__ Wc1,
                                              const float* __restrict__ Wc2,
                                              const float* __restrict__ Wc3,
                                              unsigned short* __restrict__ Wt1,
                                              unsigned short* __restrict__ Wt2,
                                              unsigned short* __restrict__ Wt3,
                                              int* __restrict__ bcur,
                                              const int* __restrict__ batch,
                                              int* __restrict__ gstart,
                                              unsigned short* __restrict__ hba,
                                              unsigned short* __restrict__ hbb,
                                              unsigned char* __restrict__ h8,
                                              unsigned int* __restrict__ hmb) {
  const int bid = blockIdx.x;
  const int t = threadIdx.x;
  if (bid < 384) {
    const float* W = (bid < 128) ? Wc1 : (bid < 256) ? Wc2 : Wc3;
    unsigned short* Wt = (bid < 128) ? Wt1 : (bid < 256) ? Wt2 : Wt3;
    int idx = (bid & 127) * 256 + t;  // 0..32767
    int k = idx >> 7;
    int n = idx & 127;
    Wt[n * 256 + k] = f2b(W[k * DD + n]);
  } else if (bid == 384) {
    if (t < NB) bcur[t] = t * MAXBE;
    if (t >= 128 && t <= 128 + NG) {
      int g = t - 128;
      int lo = 0, hi = NN;
      while (lo < hi) {
        int mid = (lo + hi) >> 1;
        if (batch[mid] < g) lo = mid + 1; else hi = mid;
      }
      gstart[g] = lo;
    }
  } else if (bid == 385) {
    unsigned int* p = reinterpret_cast<unsigned int*>(hba + (size_t)NN * DD);
    for (int i = t; i < (NNP - NN) * DD / 2; i += 256) p[i] = 0;
  } else if (bid == 386) {
    unsigned int* p = reinterpret_cast<unsigned int*>(hbb + (size_t)NN * DD);
    for (int i = t; i < (NNP - NN) * DD / 2; i += 256) p[i] = 0;
  } else if (bid == 387) {
    unsigned int* p = reinterpret_cast<unsigned int*>(h8 + (size_t)NN * DD);
    for (int i = t; i < (NNP - NN) * DD / 4; i += 256) p[i] = 0;
  } else {
    unsigned int* p = hmb + (size_t)NN * 64;
    for (int i = t; i < (NNP - NN) * 64; i += 256) p[i] = 0;
  }
}

// ---------------------------------------------------------------- binned scatter (fixed regions)
__global__ __launch_bounds__(512) void k_bscatter(const int* __restrict__ src,
                                                  const int* __restrict__ dst,
                                                  int* __restrict__ bcur,
                                                  unsigned int* __restrict__ bents) {
  __shared__ int lh[NB], lbase[NB], gbase[NB], lcnt[NB];
  __shared__ int stmp[256];
  __shared__ unsigned int sbuf[CH];
  const int t = threadIdx.x;
  const int e0 = blockIdx.x * CH;
  const int n = min(CH, NE - e0);

  for (int i = t; i < NB; i += 512) { lh[i] = 0; lcnt[i] = 0; }
  __syncthreads();

  unsigned int ent[16];
  int eb[16];
#pragma unroll
  for (int k = 0; k < 16; ++k) {
    int i = k * 512 + t;
    if (i < n) {
      int s = src[e0 + i], d = dst[e0 + i];
      ent[k] = ((unsigned)d << 16) | (unsigned)s;  // both < 65536
      eb[k] = d >> BSHIFT;
      atomicAdd(&lh[eb[k]], 1);
    } else {
      eb[k] = -1;
    }
  }
  __syncthreads();
  if (t < 256) stmp[t] = (t < NB) ? lh[t] : 0;
  __syncthreads();
  for (int off = 1; off < 256; off <<= 1) {
    int v = 0;
    if (t < 256 && t >= off) v = stmp[t - off];
    __syncthreads();
    if (t < 256) stmp[t] += v;
    __syncthreads();
  }
  if (t < NB) lbase[t] = (t == 0) ? 0 : stmp[t - 1];
  __syncthreads();
  if (t < NB && lh[t] > 0) gbase[t] = atomicAdd(&bcur[t], lh[t]);
  __syncthreads();
#pragma unroll
  for (int k = 0; k < 16; ++k) {
    if (eb[k] >= 0) {
      int r = atomicAdd(&lcnt[eb[k]], 1);
      sbuf[lbase[eb[k]] + r] = ent[k];
    }
  }
  __syncthreads();
  for (int i = t; i < n; i += 512) {
    unsigned int e = sbuf[i];
    int b = e >> 24;
    int pos = gbase[b] + (i - lbase[b]);
    if (pos < (b + 1) * MAXBE) bents[pos] = e;  // overflow guard (statistically never)
  }
}

// ---------------------------------------------------------------- per-bucket counting sort
__global__ __launch_bounds__(512) void k_sort(const unsigned int* __restrict__ bents,
                                              const int* __restrict__ bcur,
                                              int* __restrict__ prowptr,
                                              int* __restrict__ degv,
                                              unsigned short* __restrict__ csr16) {
  __shared__ int lh[256], lsc[256], plsc[256], lc2[256];
  const int b = blockIdx.x, t = threadIdx.x;
  const int base = b * MAXBE;
  const int nb = min(bcur[b] - base, MAXBE);
  const int pbase = b * MAXPB;

  if (t < 256) { lh[t] = 0; lc2[t] = 0; }
  __syncthreads();
  for (int i = t; i < nb; i += 512)
    atomicAdd(&lh[(bents[base + i] >> 16) & 255], 1);
  __syncthreads();
  if (t < 256) { lsc[t] = lh[t]; plsc[t] = (lh[t] + 31) & ~31; }
  __syncthreads();
  for (int off = 1; off < 256; off <<= 1) {
    int v = 0, pv = 0;
    if (t < 256 && t >= off) { v = lsc[t - off]; pv = plsc[t - off]; }
    __syncthreads();
    if (t < 256) { lsc[t] += v; plsc[t] += pv; }
    __syncthreads();
  }
  int ex = 0, pex = 0;
  if (t < 256) { ex = (t == 0) ? 0 : lsc[t - 1]; pex = (t == 0) ? 0 : plsc[t - 1]; }
  __syncthreads();
  if (t < 256) {
    lsc[t] = ex;
    plsc[t] = pex;
    int gnode = b * 256 + t;
    if (gnode < NN) { prowptr[gnode] = pbase + pex; degv[gnode] = lh[t]; }
  }
  __syncthreads();
  for (int i = t; i < nb; i += 512) {
    unsigned int e = bents[base + i];
    int dl = (e >> 16) & 255;
    int r = atomicAdd(&lc2[dl], 1);
    csr16[pbase + plsc[dl] + r] = (unsigned short)(e & 0xFFFF);
  }
  __syncthreads();
  if (t < 256) {
    int d = lh[t];
    int pd = (d + 31) & ~31;
    int o = pbase + plsc[t];
    for (int k = d; k < pd; ++k) csr16[o + k] = (unsigned short)NN;  // sentinel -> zero row
  }
}

// ---------------------------------------------------------------- embed: relu(LN(x@W+b)) -> bf16 + fp8
__global__ __launch_bounds__(256) void k_embed(const float* __restrict__ x,
                                               const float* __restrict__ W,
                                               const float* __restrict__ b,
                                               const float* __restrict__ gamma,
                                               const float* __restrict__ beta,
                                               unsigned short* __restrict__ hout,
                                               unsigned char* __restrict__ h8) {
  const int wid = threadIdx.x >> 6;
  const int lane = threadIdx.x & 63;
  const int node = blockIdx.x * 4 + wid;
  if (node >= NN) return;
  float xr[FIN];
#pragma unroll
  for (int k = 0; k < FIN; ++k) xr[k] = x[node * FIN + k];
  const int c0 = lane, c1 = lane + 64;
  float a0 = b[c0], a1 = b[c1];
#pragma unroll
  for (int k = 0; k < FIN; ++k) {
    a0 += xr[k] * W[k * DD + c0];
    a1 += xr[k] * W[k * DD + c1];
  }
  float s = a0 + a1;
#pragma unroll
  for (int m = 1; m < 64; m <<= 1) s += __shfl_xor(s, m, 64);
  float mean = s * (1.f / DD);
  float d0 = a0 - mean, d1 = a1 - mean;
  float v = d0 * d0 + d1 * d1;
#pragma unroll
  for (int m = 1; m < 64; m <<= 1) v += __shfl_xor(v, m, 64);
  float r = rsqrtf(v * (1.f / DD) + LN_EPS);
  float o0 = fmaxf(d0 * r * gamma[c0] + beta[c0], 0.f);
  float o1 = fmaxf(d1 * r * gamma[c1] + beta[c1], 0.f);
  hout[(size_t)node * DD + c0] = f2b(o0);
  hout[(size_t)node * DD + c1] = f2b(o1);
  h8[(size_t)node * DD + c0] = f2e4m3(o0);
  h8[(size_t)node * DD + c1] = f2e4m3(o1);
}

// ---------------------------------------------------------------- scatter-mean (fp8 gather)
__global__ __launch_bounds__(256) void k_aggr(const unsigned char* __restrict__ h8,
                                              const int* __restrict__ prowptr,
                                              const int* __restrict__ degv,
                                              const unsigned short* __restrict__ csr16,
                                              unsigned int* __restrict__ hmb) {
  const int wid = __builtin_amdgcn_readfirstlane(threadIdx.x >> 6);
  const int l = threadIdx.x & 63;
  const int node = blockIdx.x * 4 + wid;   // grid covers exactly NN
  const int pbeg = __builtin_amdgcn_readfirstlane(prowptr[node]);
  const int deg = __builtin_amdgcn_readfirstlane(degv[node]);
  const int nch = (deg + 31) >> 5;
  const unsigned int* __restrict__ cp =
      reinterpret_cast<const unsigned int*>(csr16 + pbeg);  // uniform -> scalar loads
  float a0 = 0.f, a1 = 0.f;
  for (int c = 0; c < nch; ++c) {
#pragma unroll
    for (int q = 0; q < 16; ++q) {
      unsigned int pair = cp[c * 16 + q];
      const unsigned short* r0 =
          reinterpret_cast<const unsigned short*>(h8 + (size_t)(pair & 0xFFFFu) * DD);
      const unsigned short* r1 =
          reinterpret_cast<const unsigned short*>(h8 + (size_t)(pair >> 16) * DD);
      unsigned int u0 = r0[l];
      unsigned int u1 = r1[l];
      f32x2 d0 = __builtin_amdgcn_cvt_pk_f32_fp8((int)u0, false);
      f32x2 d1 = __builtin_amdgcn_cvt_pk_f32_fp8((int)u1, false);
      a0 += d0.x + d1.x;
      a1 += d0.y + d1.y;
    }
  }
  float inv = 1.f / (float)max(deg, 1);
  unsigned int o = ((unsigned int)f2b(a1 * inv) << 16) | (unsigned int)f2b(a0 * inv);
  hmb[(size_t)node * 64 + l] = o;   // channels 2l (low), 2l+1 (high)
}

// ---------------------------------------------------------------- MFMA linear(256->128)+LN+ReLU, v3
// 512 thr (8 waves), 64 nodes/block; swapped operands (D[ch][node]) for vector stores.
// launch_bounds(512,4): VGPR cap 128 -> all frag loads held in flight (fixes the
// VGPR=32 load-concurrency starvation seen in rounds 8-9).
template <int OUT_BF16>
__global__ __launch_bounds__(512, 4) void k_lin_mfma(const unsigned short* __restrict__ hb,
                                                     const unsigned short* __restrict__ hmb,
                                                     const unsigned short* __restrict__ Wt,
                                                     const float* __restrict__ bias,
                                                     const float* __restrict__ gamma,
                                                     const float* __restrict__ beta,
                                                     void* __restrict__ outv,
                                                     unsigned char* __restrict__ h8out) {
  __shared__ float sred[4][16][2][2];  // [group][node16][half][{s,q}]
  const int tid = threadIdx.x;
  const int w = tid >> 6;
  const int l = tid & 63;
  const int g = w & 3;          // node group (16 nodes)
  const int hh = w >> 2;        // channel half: t = hh*4 + t2
  const int c16 = l & 15;
  const int kg = l >> 4;
  const int node = blockIdx.x * 64 + g * 16 + c16;

  // B-frags: this lane's node features (self 128 | mean 128) — 8 independent 16B loads
  const unsigned short* brow_self = hb + (size_t)node * DD + kg * 8;
  const unsigned short* brow_mean = hmb + (size_t)node * DD + kg * 8;
  bf16x8 bfr[8];
#pragma unroll
  for (int kc = 0; kc < 4; ++kc)
    bfr[kc] = *reinterpret_cast<const bf16x8*>(brow_self + kc * 32);
#pragma unroll
  for (int kc = 0; kc < 4; ++kc)
    bfr[4 + kc] = *reinterpret_cast<const bf16x8*>(brow_mean + kc * 32);

  f32x4 acc[4];
#pragma unroll
  for (int t2 = 0; t2 < 4; ++t2) acc[t2] = (f32x4){0.f, 0.f, 0.f, 0.f};

#pragma unroll
  for (int t2 = 0; t2 < 4; ++t2) {
    const unsigned short* arow = Wt + (size_t)((hh * 4 + t2) * 16 + c16) * 256 + kg * 8;
    bf16x8 afr[8];
#pragma unroll
    for (int kc = 0; kc < 8; ++kc)   // 8 independent 16B loads, batched
      afr[kc] = *reinterpret_cast<const bf16x8*>(arow + kc * 32);
#pragma unroll
    for (int kc = 0; kc < 8; ++kc)
      acc[t2] = __builtin_amdgcn_mfma_f32_16x16x32_bf16(afr[kc], bfr[kc], acc[t2], 0, 0, 0);
  }

  // bias add: channel = (hh*4+t2)*16 + kg*4 + i
#pragma unroll
  for (int t2 = 0; t2 < 4; ++t2) {
    float4 bv = reinterpret_cast<const float4*>(bias)[(hh * 4 + t2) * 4 + kg];
    acc[t2][0] += bv.x; acc[t2][1] += bv.y; acc[t2][2] += bv.z; acc[t2][3] += bv.w;
  }

  // LN partials for this half (64 channels): s = sum, q = sumsq
  float s = 0.f, q = 0.f;
#pragma unroll
  for (int t2 = 0; t2 < 4; ++t2)
#pragma unroll
    for (int i = 0; i < 4; ++i) { float v = acc[t2][i]; s += v; q += v * v; }
#pragma unroll
  for (int m = 16; m < 64; m <<= 1) {
    s += __shfl_xor(s, m, 64);
    q += __shfl_xor(q, m, 64);
  }
  if (kg == 0) { sred[g][c16][hh][0] = s; sred[g][c16][hh][1] = q; }
  __syncthreads();
  float st = sred[g][c16][0][0] + sred[g][c16][1][0];
  float qt = sred[g][c16][0][1] + sred[g][c16][1][1];
  float mean = st * (1.f / DD);
  float var = fmaxf(qt * (1.f / DD) - mean * mean, 0.f);
  float r = rsqrtf(var + LN_EPS);

  if (node < NN) {
#pragma unroll
    for (int t2 = 0; t2 < 4; ++t2) {
      int cbase = (hh * 4 + t2) * 16 + kg * 4;
      float4 gv = reinterpret_cast<const float4*>(gamma)[cbase >> 2];
      float4 btv = reinterpret_cast<const float4*>(beta)[cbase >> 2];
      float v0 = fmaxf((acc[t2][0] - mean) * r * gv.x + btv.x, 0.f);
      float v1 = fmaxf((acc[t2][1] - mean) * r * gv.y + btv.y, 0.f);
      float v2 = fmaxf((acc[t2][2] - mean) * r * gv.z + btv.z, 0.f);
      float v3 = fmaxf((acc[t2][3] - mean) * r * gv.w + btv.w, 0.f);
      if (OUT_BF16) {
        ushort4 ob;
        ob.x = f2b(v0); ob.y = f2b(v1); ob.z = f2b(v2); ob.w = f2b(v3);
        *reinterpret_cast<ushort4*>((unsigned short*)outv + (size_t)node * DD + cbase) = ob;
        int p8 = __builtin_amdgcn_cvt_pk_fp8_f32(v0, v1, 0, false);
        p8 = __builtin_amdgcn_cvt_pk_fp8_f32(v2, v3, p8, true);
        *reinterpret_cast<unsigned int*>(h8out + (size_t)node * DD + cbase) = (unsigned int)p8;
      } else {
        float4 of = make_float4(v0, v1, v2, v3);
        *reinterpret_cast<float4*>((float*)outv + (size_t)node * DD + cbase) = of;
      }
    }
  }
}

// ---------------------------------------------------------------- graph pooling (mean+max)
__global__ __launch_bounds__(128) void k_pool1(const float* __restrict__ ne,
                                               const int* __restrict__ gstart,
                                               float* __restrict__ part) {
  const int g = blockIdx.x / PSEG;
  const int sg = blockIdx.x % PSEG;
  const int c = threadIdx.x;
  const int beg = gstart[g], end = gstart[g + 1];
  const int len = end - beg;
  const int per = (len + PSEG - 1) / PSEG;
  const int n0 = beg + sg * per;
  const int n1 = min(n0 + per, end);
  float s = 0.f, mx = -INFINITY;
  for (int n = n0; n < n1; ++n) {
    float v = ne[(size_t)n * DD + c];
    s += v;
    mx = fmaxf(mx, v);
  }
  part[(size_t)(g * PSEG + sg) * 256 + c] = s;
  part[(size_t)(g * PSEG + sg) * 256 + 128 + c] = mx;
}

__global__ __launch_bounds__(256) void k_pool2(const float* __restrict__ part,
                                               const int* __restrict__ gstart,
                                               float* __restrict__ gout) {
  const int g = blockIdx.x;
  const int c = threadIdx.x;
  const bool isMax = c >= 128;
  float acc = isMax ? -INFINITY : 0.f;
  for (int sg = 0; sg < PSEG; ++sg) {
    float v = part[(size_t)(g * PSEG + sg) * 256 + c];
    acc = isMax ? fmaxf(acc, v) : (acc + v);
  }
  if (!isMax) acc /= (float)max(gstart[g + 1] - gstart[g], 1);
  gout[(size_t)g * 256 + c] = acc;
}

// ---------------------------------------------------------------- launch
static inline size_t align_up(size_t v, size_t a) { return (v + a - 1) & ~(a - 1); }

extern "C" void kernel_launch(void* const* d_in, const int* in_sizes, int n_in,
                              void* d_out, int out_size, void* d_ws, size_t ws_size,
                              hipStream_t stream) {
  const float* x     = (const float*)d_in[0];
  const int*   ei    = (const int*)d_in[1];
  const int*   batch = (const int*)d_in[2];
  const float* W_emb = (const float*)d_in[3];
  const float* b_emb = (const float*)d_in[4];
  const float* g0    = (const float*)d_in[5];
  const float* bt0   = (const float*)d_in[6];
  const float* Wc1   = (const float*)d_in[7];
  const float* bc1   = (const float*)d_in[8];
  const float* g1    = (const float*)d_in[9];
  const float* bt1   = (const float*)d_in[10];
  const float* Wc2   = (const float*)d_in[11];
  const float* bc2   = (const float*)d_in[12];
  const float* g2    = (const float*)d_in[13];
  const float* bt2   = (const float*)d_in[14];
  const float* Wc3   = (const float*)d_in[15];
  const float* bc3   = (const float*)d_in[16];
  const float* g3    = (const float*)d_in[17];
  const float* bt3   = (const float*)d_in[18];

  const int* src = ei;
  const int* dst = ei + NE;

  float* out_node  = (float*)d_out;                     // N*D fp32
  float* out_graph = (float*)d_out + (size_t)NN * DD;   // G*256 fp32

  char* p = (char*)d_ws;
  auto alloc = [&](size_t bytes) { char* r = p; p += align_up(bytes, 256); return r; };
  int*            prowptr = (int*)alloc((size_t)NN * sizeof(int));
  int*            degv    = (int*)alloc((size_t)NN * sizeof(int));
  int*            bcur    = (int*)alloc(NB * sizeof(int));
  int*            gstart  = (int*)alloc((NG + 1) * sizeof(int));
  unsigned int*   bents   = (unsigned int*)alloc((size_t)NB * MAXBE * 4);
  unsigned short* csr16   = (unsigned short*)alloc((size_t)NB * MAXPB * 2);
  unsigned short* hba     = (unsigned short*)alloc((size_t)NNP * DD * 2);
  unsigned short* hbb     = (unsigned short*)alloc((size_t)NNP * DD * 2);
  unsigned char*  h8      = (unsigned char*)alloc((size_t)NNP * DD);
  unsigned int*   hmb     = (unsigned int*)alloc((size_t)NNP * 64 * 4);
  unsigned short* Wt1     = (unsigned short*)alloc(128 * 256 * 2);
  unsigned short* Wt2     = (unsigned short*)alloc(128 * 256 * 2);
  unsigned short* Wt3     = (unsigned short*)alloc(128 * 256 * 2);
  float*          ppart   = (float*)alloc((size_t)NG * PSEG * 256 * sizeof(float));

  // prep: Wt x3, bcur init, gstart, pad zeroing   (1 dispatch)
  k_prep<<<388, 256, 0, stream>>>(Wc1, Wc2, Wc3, Wt1, Wt2, Wt3, bcur, batch, gstart,
                                  hba, hbb, h8, hmb);
  // CSR build (2 dispatches)
  k_bscatter<<<(NE + CH - 1) / CH, 512, 0, stream>>>(src, dst, bcur, bents);
  k_sort<<<NB, 512, 0, stream>>>(bents, bcur, prowptr, degv, csr16);

  // embed -> bf16 + fp8
  k_embed<<<NN / 4, 256, 0, stream>>>(x, W_emb, b_emb, g0, bt0, hba, h8);

  const int LIN_GRID = NNP / 64;   // 782
  const int AGGR_GRID = NN / 4;    // 12500 (wave per node)
  // layer 1
  k_aggr<<<AGGR_GRID, 256, 0, stream>>>(h8, prowptr, degv, csr16, hmb);
  k_lin_mfma<1><<<LIN_GRID, 512, 0, stream>>>(hba, (unsigned short*)hmb, Wt1, bc1, g1, bt1, hbb, h8);
  // layer 2
  k_aggr<<<AGGR_GRID, 256, 0, stream>>>(h8, prowptr, degv, csr16, hmb);
  k_lin_mfma<1><<<LIN_GRID, 512, 0, stream>>>(hbb, (unsigned short*)hmb, Wt2, bc2, g2, bt2, hba, h8);
  // layer 3
  k_aggr<<<AGGR_GRID, 256, 0, stream>>>(h8, prowptr, degv, csr16, hmb);
  k_lin_mfma<0><<<LIN_GRID, 512, 0, stream>>>(hba, (unsigned short*)hmb, Wt3, bc3, g3, bt3, out_node, h8);

  // pooling
  k_pool1<<<NG * PSEG, 128, 0, stream>>>(out_node, gstart, ppart);
  k_pool2<<<NG, 256, 0, stream>>>(ppart, gstart, out_graph);
}

// Round 11
// 210.786 us; speedup vs baseline: 1.3476x; 1.3476x over previous
//
#include <hip/hip_runtime.h>
#include <hip/hip_bf16.h>
#include <math.h>

#define NN 50000
#define NNP 50048          // padded rows
#define NE 1600000
#define FIN 9
#define DD 128
#define NG 64
#define PSEG 16
#define LN_EPS 1e-5f

// binning: 196 buckets x 256 dst nodes, fixed regions
#define NB 196
#define BSHIFT 8
#define CH 8192            // edges per bscatter block
#define MAXBE 12288        // raw entries reserved per bucket (mean 8163, +45 sigma)
#define MAXPB 20480        // padded csr entries reserved per bucket

typedef __attribute__((ext_vector_type(8))) short bf16x8;
typedef __attribute__((ext_vector_type(4))) float f32x4;
typedef __attribute__((ext_vector_type(2))) float f32x2;

static __device__ __forceinline__ unsigned short f2b(float f) {
  __hip_bfloat16 h = __float2bfloat16(f);
  return __builtin_bit_cast(unsigned short, h);
}
static __device__ __forceinline__ unsigned char f2e4m3(float f) {
  int r = __builtin_amdgcn_cvt_pk_fp8_f32(f, f, 0, false);
  return (unsigned char)(r & 0xFF);
}

// ---------------------------------------------------------------- prep: Wt x3, bcur, gstart, pads
__global__ __launch_bounds__(256) void k_prep(const float* __restrict__ Wc1,
                                              const float* __restrict__ Wc2,
                                              const float* __restrict__ Wc3,
                                              unsigned short* __restrict__ Wt1,
                                              unsigned short* __restrict__ Wt2,
                                              unsigned short* __restrict__ Wt3,
                                              int* __restrict__ bcur,
                                              const int* __restrict__ batch,
                                              int* __restrict__ gstart,
                                              unsigned short* __restrict__ hba,
                                              unsigned short* __restrict__ hbb,
                                              unsigned char* __restrict__ h8,
                                              unsigned int* __restrict__ hmb) {
  const int bid = blockIdx.x;
  const int t = threadIdx.x;
  if (bid < 384) {
    const float* W = (bid < 128) ? Wc1 : (bid < 256) ? Wc2 : Wc3;
    unsigned short* Wt = (bid < 128) ? Wt1 : (bid < 256) ? Wt2 : Wt3;
    int idx = (bid & 127) * 256 + t;  // 0..32767
    int k = idx >> 7;
    int n = idx & 127;
    Wt[n * 256 + k] = f2b(W[k * DD + n]);
  } else if (bid == 384) {
    if (t < NB) bcur[t] = t * MAXBE;
    if (t >= 128 && t <= 128 + NG) {
      int g = t - 128;
      int lo = 0, hi = NN;
      while (lo < hi) {
        int mid = (lo + hi) >> 1;
        if (batch[mid] < g) lo = mid + 1; else hi = mid;
      }
      gstart[g] = lo;
    }
  } else if (bid == 385) {
    unsigned int* p = reinterpret_cast<unsigned int*>(hba + (size_t)NN * DD);
    for (int i = t; i < (NNP - NN) * DD / 2; i += 256) p[i] = 0;
  } else if (bid == 386) {
    unsigned int* p = reinterpret_cast<unsigned int*>(hbb + (size_t)NN * DD);
    for (int i = t; i < (NNP - NN) * DD / 2; i += 256) p[i] = 0;
  } else if (bid == 387) {
    unsigned int* p = reinterpret_cast<unsigned int*>(h8 + (size_t)NN * DD);
    for (int i = t; i < (NNP - NN) * DD / 4; i += 256) p[i] = 0;
  } else {
    unsigned int* p = hmb + (size_t)NN * 64;
    for (int i = t; i < (NNP - NN) * 64; i += 256) p[i] = 0;
  }
}

// ---------------------------------------------------------------- binned scatter (fixed regions)
__global__ __launch_bounds__(512) void k_bscatter(const int* __restrict__ src,
                                                  const int* __restrict__ dst,
                                                  int* __restrict__ bcur,
                                                  unsigned int* __restrict__ bents) {
  __shared__ int lh[NB], lbase[NB], gbase[NB], lcnt[NB];
  __shared__ int stmp[256];
  __shared__ unsigned int sbuf[CH];
  const int t = threadIdx.x;
  const int e0 = blockIdx.x * CH;
  const int n = min(CH, NE - e0);

  for (int i = t; i < NB; i += 512) { lh[i] = 0; lcnt[i] = 0; }
  __syncthreads();

  unsigned int ent[16];
  int eb[16];
#pragma unroll
  for (int k = 0; k < 16; ++k) {
    int i = k * 512 + t;
    if (i < n) {
      int s = src[e0 + i], d = dst[e0 + i];
      ent[k] = ((unsigned)d << 16) | (unsigned)s;  // both < 65536
      eb[k] = d >> BSHIFT;
      atomicAdd(&lh[eb[k]], 1);
    } else {
      eb[k] = -1;
    }
  }
  __syncthreads();
  if (t < 256) stmp[t] = (t < NB) ? lh[t] : 0;
  __syncthreads();
  for (int off = 1; off < 256; off <<= 1) {
    int v = 0;
    if (t < 256 && t >= off) v = stmp[t - off];
    __syncthreads();
    if (t < 256) stmp[t] += v;
    __syncthreads();
  }
  if (t < NB) lbase[t] = (t == 0) ? 0 : stmp[t - 1];
  __syncthreads();
  if (t < NB && lh[t] > 0) gbase[t] = atomicAdd(&bcur[t], lh[t]);
  __syncthreads();
#pragma unroll
  for (int k = 0; k < 16; ++k) {
    if (eb[k] >= 0) {
      int r = atomicAdd(&lcnt[eb[k]], 1);
      sbuf[lbase[eb[k]] + r] = ent[k];
    }
  }
  __syncthreads();
  for (int i = t; i < n; i += 512) {
    unsigned int e = sbuf[i];
    int b = e >> 24;
    int pos = gbase[b] + (i - lbase[b]);
    if (pos < (b + 1) * MAXBE) bents[pos] = e;  // overflow guard (statistically never)
  }
}

// ---------------------------------------------------------------- per-bucket counting sort
__global__ __launch_bounds__(512) void k_sort(const unsigned int* __restrict__ bents,
                                              const int* __restrict__ bcur,
                                              int* __restrict__ prowptr,
                                              int* __restrict__ degv,
                                              unsigned short* __restrict__ csr16) {
  __shared__ int lh[256], lsc[256], plsc[256], lc2[256];
  const int b = blockIdx.x, t = threadIdx.x;
  const int base = b * MAXBE;
  const int nb = min(bcur[b] - base, MAXBE);
  const int pbase = b * MAXPB;

  if (t < 256) { lh[t] = 0; lc2[t] = 0; }
  __syncthreads();
  for (int i = t; i < nb; i += 512)
    atomicAdd(&lh[(bents[base + i] >> 16) & 255], 1);
  __syncthreads();
  if (t < 256) { lsc[t] = lh[t]; plsc[t] = (lh[t] + 31) & ~31; }
  __syncthreads();
  for (int off = 1; off < 256; off <<= 1) {
    int v = 0, pv = 0;
    if (t < 256 && t >= off) { v = lsc[t - off]; pv = plsc[t - off]; }
    __syncthreads();
    if (t < 256) { lsc[t] += v; plsc[t] += pv; }
    __syncthreads();
  }
  int ex = 0, pex = 0;
  if (t < 256) { ex = (t == 0) ? 0 : lsc[t - 1]; pex = (t == 0) ? 0 : plsc[t - 1]; }
  __syncthreads();
  if (t < 256) {
    lsc[t] = ex;
    plsc[t] = pex;
    int gnode = b * 256 + t;
    if (gnode < NN) { prowptr[gnode] = pbase + pex; degv[gnode] = lh[t]; }
  }
  __syncthreads();
  for (int i = t; i < nb; i += 512) {
    unsigned int e = bents[base + i];
    int dl = (e >> 16) & 255;
    int r = atomicAdd(&lc2[dl], 1);
    csr16[pbase + plsc[dl] + r] = (unsigned short)(e & 0xFFFF);
  }
  __syncthreads();
  if (t < 256) {
    int d = lh[t];
    int pd = (d + 31) & ~31;
    int o = pbase + plsc[t];
    for (int k = d; k < pd; ++k) csr16[o + k] = (unsigned short)NN;  // sentinel -> zero row
  }
}

// ---------------------------------------------------------------- embed: relu(LN(x@W+b)) -> bf16 + fp8
__global__ __launch_bounds__(256) void k_embed(const float* __restrict__ x,
                                               const float* __restrict__ W,
                                               const float* __restrict__ b,
                                               const float* __restrict__ gamma,
                                               const float* __restrict__ beta,
                                               unsigned short* __restrict__ hout,
                                               unsigned char* __restrict__ h8) {
  const int wid = threadIdx.x >> 6;
  const int lane = threadIdx.x & 63;
  const int node = blockIdx.x * 4 + wid;
  if (node >= NN) return;
  float xr[FIN];
#pragma unroll
  for (int k = 0; k < FIN; ++k) xr[k] = x[node * FIN + k];
  const int c0 = lane, c1 = lane + 64;
  float a0 = b[c0], a1 = b[c1];
#pragma unroll
  for (int k = 0; k < FIN; ++k) {
    a0 += xr[k] * W[k * DD + c0];
    a1 += xr[k] * W[k * DD + c1];
  }
  float s = a0 + a1;
#pragma unroll
  for (int m = 1; m < 64; m <<= 1) s += __shfl_xor(s, m, 64);
  float mean = s * (1.f / DD);
  float d0 = a0 - mean, d1 = a1 - mean;
  float v = d0 * d0 + d1 * d1;
#pragma unroll
  for (int m = 1; m < 64; m <<= 1) v += __shfl_xor(v, m, 64);
  float r = rsqrtf(v * (1.f / DD) + LN_EPS);
  float o0 = fmaxf(d0 * r * gamma[c0] + beta[c0], 0.f);
  float o1 = fmaxf(d1 * r * gamma[c1] + beta[c1], 0.f);
  hout[(size_t)node * DD + c0] = f2b(o0);
  hout[(size_t)node * DD + c1] = f2b(o1);
  h8[(size_t)node * DD + c0] = f2e4m3(o0);
  h8[(size_t)node * DD + c1] = f2e4m3(o1);
}

// ---------------------------------------------------------------- scatter-mean (fp8 gather)
__global__ __launch_bounds__(256) void k_aggr(const unsigned char* __restrict__ h8,
                                              const int* __restrict__ prowptr,
                                              const int* __restrict__ degv,
                                              const unsigned short* __restrict__ csr16,
                                              unsigned int* __restrict__ hmb) {
  const int wid = __builtin_amdgcn_readfirstlane(threadIdx.x >> 6);
  const int l = threadIdx.x & 63;
  const int node = blockIdx.x * 4 + wid;   // grid covers exactly NN
  const int pbeg = __builtin_amdgcn_readfirstlane(prowptr[node]);
  const int deg = __builtin_amdgcn_readfirstlane(degv[node]);
  const int nch = (deg + 31) >> 5;
  const unsigned int* __restrict__ cp =
      reinterpret_cast<const unsigned int*>(csr16 + pbeg);  // uniform -> scalar loads
  float a0 = 0.f, a1 = 0.f;
  for (int c = 0; c < nch; ++c) {
#pragma unroll
    for (int q = 0; q < 16; ++q) {
      unsigned int pair = cp[c * 16 + q];
      const unsigned short* r0 =
          reinterpret_cast<const unsigned short*>(h8 + (size_t)(pair & 0xFFFFu) * DD);
      const unsigned short* r1 =
          reinterpret_cast<const unsigned short*>(h8 + (size_t)(pair >> 16) * DD);
      unsigned int u0 = r0[l];
      unsigned int u1 = r1[l];
      f32x2 d0 = __builtin_amdgcn_cvt_pk_f32_fp8((int)u0, false);
      f32x2 d1 = __builtin_amdgcn_cvt_pk_f32_fp8((int)u1, false);
      a0 += d0.x + d1.x;
      a1 += d0.y + d1.y;
    }
  }
  float inv = 1.f / (float)max(deg, 1);
  unsigned int o = ((unsigned int)f2b(a1 * inv) << 16) | (unsigned int)f2b(a0 * inv);
  hmb[(size_t)node * 64 + l] = o;   // channels 2l (low), 2l+1 (high)
}

// ---------------------------------------------------------------- MFMA linear(256->128)+LN+ReLU, v4
// 512 thr (8 waves), 64 nodes/block; swapped operands (D[ch][node]) for vector stores.
// W^T staged in LDS once per block (64KB, 16B-granule XOR swizzle g^=(row&7) for
// conflict-free ds_read_b128) -> inner loop has NO global loads (fixes VGPR=32
// load-concurrency starvation: compiler can't batch global loads, LDS is low-latency).
template <int OUT_BF16>
__global__ __launch_bounds__(512, 4) void k_lin_mfma(const unsigned short* __restrict__ hb,
                                                     const unsigned short* __restrict__ hmb,
                                                     const unsigned short* __restrict__ Wt,
                                                     const float* __restrict__ bias,
                                                     const float* __restrict__ gamma,
                                                     const float* __restrict__ beta,
                                                     void* __restrict__ outv,
                                                     unsigned char* __restrict__ h8out) {
  __shared__ unsigned short wlds[128 * 256];  // 64 KB, granule-swizzled rows
  __shared__ float sred[4][16][2][2];         // [group][node16][half][{s,q}]
  const int tid = threadIdx.x;
  const int w = tid >> 6;
  const int l = tid & 63;
  const int g = w & 3;          // node group (16 nodes)
  const int hh = w >> 2;        // channel half: t = hh*4 + t2
  const int c16 = l & 15;
  const int kg = l >> 4;
  const int node = blockIdx.x * 64 + g * 16 + c16;

  // ---- stage W^T -> LDS (coalesced 16B loads; swizzled 16B-granule writes)
#pragma unroll
  for (int it = 0; it < 8; ++it) {
    int idx = it * 512 + tid;      // granule id 0..4095
    int r = idx >> 5;              // row 0..127
    int gr = idx & 31;             // granule within row
    uint4 v = *reinterpret_cast<const uint4*>(Wt + (size_t)r * 256 + gr * 8);
    int gs = gr ^ (r & 7);
    *reinterpret_cast<uint4*>(wlds + (size_t)r * 256 + gs * 8) = v;
  }

  // ---- B-frags (global, 8 x 16B per lane) overlap with staging
  const unsigned short* brow_self = hb + (size_t)node * DD + kg * 8;
  const unsigned short* brow_mean = hmb + (size_t)node * DD + kg * 8;
  bf16x8 bfr[8];
#pragma unroll
  for (int kc = 0; kc < 4; ++kc)
    bfr[kc] = *reinterpret_cast<const bf16x8*>(brow_self + kc * 32);
#pragma unroll
  for (int kc = 0; kc < 4; ++kc)
    bfr[4 + kc] = *reinterpret_cast<const bf16x8*>(brow_mean + kc * 32);

  __syncthreads();

  f32x4 acc[4];
#pragma unroll
  for (int t2 = 0; t2 < 4; ++t2) acc[t2] = (f32x4){0.f, 0.f, 0.f, 0.f};

#pragma unroll
  for (int t2 = 0; t2 < 4; ++t2) {
    const int row = (hh * 4 + t2) * 16 + c16;
    const unsigned short* wr = wlds + (size_t)row * 256;
    const int sw = c16 & 7;
#pragma unroll
    for (int kc = 0; kc < 8; ++kc) {
      bf16x8 a = *reinterpret_cast<const bf16x8*>(wr + ((kc * 4 + kg) ^ sw) * 8);
      acc[t2] = __builtin_amdgcn_mfma_f32_16x16x32_bf16(a, bfr[kc], acc[t2], 0, 0, 0);
    }
  }

  // bias add: channel = (hh*4+t2)*16 + kg*4 + i
#pragma unroll
  for (int t2 = 0; t2 < 4; ++t2) {
    float4 bv = reinterpret_cast<const float4*>(bias)[(hh * 4 + t2) * 4 + kg];
    acc[t2][0] += bv.x; acc[t2][1] += bv.y; acc[t2][2] += bv.z; acc[t2][3] += bv.w;
  }

  // LN partials for this half (64 channels): s = sum, q = sumsq
  float s = 0.f, q = 0.f;
#pragma unroll
  for (int t2 = 0; t2 < 4; ++t2)
#pragma unroll
    for (int i = 0; i < 4; ++i) { float v = acc[t2][i]; s += v; q += v * v; }
#pragma unroll
  for (int m = 16; m < 64; m <<= 1) {
    s += __shfl_xor(s, m, 64);
    q += __shfl_xor(q, m, 64);
  }
  if (kg == 0) { sred[g][c16][hh][0] = s; sred[g][c16][hh][1] = q; }
  __syncthreads();
  float st = sred[g][c16][0][0] + sred[g][c16][1][0];
  float qt = sred[g][c16][0][1] + sred[g][c16][1][1];
  float mean = st * (1.f / DD);
  float var = fmaxf(qt * (1.f / DD) - mean * mean, 0.f);
  float r = rsqrtf(var + LN_EPS);

  if (node < NN) {
#pragma unroll
    for (int t2 = 0; t2 < 4; ++t2) {
      int cbase = (hh * 4 + t2) * 16 + kg * 4;
      float4 gv = reinterpret_cast<const float4*>(gamma)[cbase >> 2];
      float4 btv = reinterpret_cast<const float4*>(beta)[cbase >> 2];
      float v0 = fmaxf((acc[t2][0] - mean) * r * gv.x + btv.x, 0.f);
      float v1 = fmaxf((acc[t2][1] - mean) * r * gv.y + btv.y, 0.f);
      float v2 = fmaxf((acc[t2][2] - mean) * r * gv.z + btv.z, 0.f);
      float v3 = fmaxf((acc[t2][3] - mean) * r * gv.w + btv.w, 0.f);
      if (OUT_BF16) {
        ushort4 ob;
        ob.x = f2b(v0); ob.y = f2b(v1); ob.z = f2b(v2); ob.w = f2b(v3);
        *reinterpret_cast<ushort4*>((unsigned short*)outv + (size_t)node * DD + cbase) = ob;
        int p8 = __builtin_amdgcn_cvt_pk_fp8_f32(v0, v1, 0, false);
        p8 = __builtin_amdgcn_cvt_pk_fp8_f32(v2, v3, p8, true);
        *reinterpret_cast<unsigned int*>(h8out + (size_t)node * DD + cbase) = (unsigned int)p8;
      } else {
        float4 of = make_float4(v0, v1, v2, v3);
        *reinterpret_cast<float4*>((float*)outv + (size_t)node * DD + cbase) = of;
      }
    }
  }
}

// ---------------------------------------------------------------- graph pooling (mean+max)
__global__ __launch_bounds__(128) void k_pool1(const float* __restrict__ ne,
                                               const int* __restrict__ gstart,
                                               float* __restrict__ part) {
  const int g = blockIdx.x / PSEG;
  const int sg = blockIdx.x % PSEG;
  const int c = threadIdx.x;
  const int beg = gstart[g], end = gstart[g + 1];
  const int len = end - beg;
  const int per = (len + PSEG - 1) / PSEG;
  const int n0 = beg + sg * per;
  const int n1 = min(n0 + per, end);
  float s = 0.f, mx = -INFINITY;
  for (int n = n0; n < n1; ++n) {
    float v = ne[(size_t)n * DD + c];
    s += v;
    mx = fmaxf(mx, v);
  }
  part[(size_t)(g * PSEG + sg) * 256 + c] = s;
  part[(size_t)(g * PSEG + sg) * 256 + 128 + c] = mx;
}

__global__ __launch_bounds__(256) void k_pool2(const float* __restrict__ part,
                                               const int* __restrict__ gstart,
                                               float* __restrict__ gout) {
  const int g = blockIdx.x;
  const int c = threadIdx.x;
  const bool isMax = c >= 128;
  float acc = isMax ? -INFINITY : 0.f;
  for (int sg = 0; sg < PSEG; ++sg) {
    float v = part[(size_t)(g * PSEG + sg) * 256 + c];
    acc = isMax ? fmaxf(acc, v) : (acc + v);
  }
  if (!isMax) acc /= (float)max(gstart[g + 1] - gstart[g], 1);
  gout[(size_t)g * 256 + c] = acc;
}

// ---------------------------------------------------------------- launch
static inline size_t align_up(size_t v, size_t a) { return (v + a - 1) & ~(a - 1); }

extern "C" void kernel_launch(void* const* d_in, const int* in_sizes, int n_in,
                              void* d_out, int out_size, void* d_ws, size_t ws_size,
                              hipStream_t stream) {
  const float* x     = (const float*)d_in[0];
  const int*   ei    = (const int*)d_in[1];
  const int*   batch = (const int*)d_in[2];
  const float* W_emb = (const float*)d_in[3];
  const float* b_emb = (const float*)d_in[4];
  const float* g0    = (const float*)d_in[5];
  const float* bt0   = (const float*)d_in[6];
  const float* Wc1   = (const float*)d_in[7];
  const float* bc1   = (const float*)d_in[8];
  const float* g1    = (const float*)d_in[9];
  const float* bt1   = (const float*)d_in[10];
  const float* Wc2   = (const float*)d_in[11];
  const float* bc2   = (const float*)d_in[12];
  const float* g2    = (const float*)d_in[13];
  const float* bt2   = (const float*)d_in[14];
  const float* Wc3   = (const float*)d_in[15];
  const float* bc3   = (const float*)d_in[16];
  const float* g3    = (const float*)d_in[17];
  const float* bt3   = (const float*)d_in[18];

  const int* src = ei;
  const int* dst = ei + NE;

  float* out_node  = (float*)d_out;                     // N*D fp32
  float* out_graph = (float*)d_out + (size_t)NN * DD;   // G*256 fp32

  char* p = (char*)d_ws;
  auto alloc = [&](size_t bytes) { char* r = p; p += align_up(bytes, 256); return r; };
  int*            prowptr = (int*)alloc((size_t)NN * sizeof(int));
  int*            degv    = (int*)alloc((size_t)NN * sizeof(int));
  int*            bcur    = (int*)alloc(NB * sizeof(int));
  int*            gstart  = (int*)alloc((NG + 1) * sizeof(int));
  unsigned int*   bents   = (unsigned int*)alloc((size_t)NB * MAXBE * 4);
  unsigned short* csr16   = (unsigned short*)alloc((size_t)NB * MAXPB * 2);
  unsigned short* hba     = (unsigned short*)alloc((size_t)NNP * DD * 2);
  unsigned short* hbb     = (unsigned short*)alloc((size_t)NNP * DD * 2);
  unsigned char*  h8      = (unsigned char*)alloc((size_t)NNP * DD);
  unsigned int*   hmb     = (unsigned int*)alloc((size_t)NNP * 64 * 4);
  unsigned short* Wt1     = (unsigned short*)alloc(128 * 256 * 2);
  unsigned short* Wt2     = (unsigned short*)alloc(128 * 256 * 2);
  unsigned short* Wt3     = (unsigned short*)alloc(128 * 256 * 2);
  float*          ppart   = (float*)alloc((size_t)NG * PSEG * 256 * sizeof(float));

  // prep: Wt x3, bcur init, gstart, pad zeroing   (1 dispatch)
  k_prep<<<388, 256, 0, stream>>>(Wc1, Wc2, Wc3, Wt1, Wt2, Wt3, bcur, batch, gstart,
                                  hba, hbb, h8, hmb);
  // CSR build (2 dispatches)
  k_bscatter<<<(NE + CH - 1) / CH, 512, 0, stream>>>(src, dst, bcur, bents);
  k_sort<<<NB, 512, 0, stream>>>(bents, bcur, prowptr, degv, csr16);

  // embed -> bf16 + fp8
  k_embed<<<NN / 4, 256, 0, stream>>>(x, W_emb, b_emb, g0, bt0, hba, h8);

  const int LIN_GRID = NNP / 64;   // 782
  const int AGGR_GRID = NN / 4;    // 12500 (wave per node)
  // layer 1
  k_aggr<<<AGGR_GRID, 256, 0, stream>>>(h8, prowptr, degv, csr16, hmb);
  k_lin_mfma<1><<<LIN_GRID, 512, 0, stream>>>(hba, (unsigned short*)hmb, Wt1, bc1, g1, bt1, hbb, h8);
  // layer 2
  k_aggr<<<AGGR_GRID, 256, 0, stream>>>(h8, prowptr, degv, csr16, hmb);
  k_lin_mfma<1><<<LIN_GRID, 512, 0, stream>>>(hbb, (unsigned short*)hmb, Wt2, bc2, g2, bt2, hba, h8);
  // layer 3
  k_aggr<<<AGGR_GRID, 256, 0, stream>>>(h8, prowptr, degv, csr16, hmb);
  k_lin_mfma<0><<<LIN_GRID, 512, 0, stream>>>(hba, (unsigned short*)hmb, Wt3, bc3, g3, bt3, out_node, h8);

  // pooling
  k_pool1<<<NG * PSEG, 128, 0, stream>>>(out_node, gstart, ppart);
  k_pool2<<<NG, 256, 0, stream>>>(ppart, gstart, out_graph);
}

// Round 12
// 206.554 us; speedup vs baseline: 1.3752x; 1.0205x over previous
//
#include <hip/hip_runtime.h>
#include <hip/hip_bf16.h>
#include <math.h>

#define NN 50000
#define NNP 50048          // padded rows
#define NE 1600000
#define FIN 9
#define DD 128
#define NG 64
#define PSEG 16
#define LN_EPS 1e-5f

// binning: 196 buckets x 256 dst nodes, fixed regions
#define NB 196
#define BSHIFT 8
#define CH 8192            // edges per bscatter block
#define MAXBE 12288        // raw entries reserved per bucket (mean 8163, +45 sigma)
#define MAXPB 20480        // padded csr entries reserved per bucket
#define EMB0 387           // first embed block in k_prep

typedef __attribute__((ext_vector_type(8))) short bf16x8;
typedef __attribute__((ext_vector_type(4))) float f32x4;
typedef __attribute__((ext_vector_type(2))) float f32x2;

static __device__ __forceinline__ unsigned short f2b(float f) {
  __hip_bfloat16 h = __float2bfloat16(f);
  return __builtin_bit_cast(unsigned short, h);
}
static __device__ __forceinline__ unsigned char f2e4m3(float f) {
  int r = __builtin_amdgcn_cvt_pk_fp8_f32(f, f, 0, false);
  return (unsigned char)(r & 0xFF);
}

// ---------------------------------------------------------------- prep (+embed fused)
// bid<384: Wt transpose x3 | 384: bcur+gstart | 385: pad rows | 386: gout zero | >=387: embed
__global__ __launch_bounds__(256) void k_prep(const float* __restrict__ Wc1,
                                              const float* __restrict__ Wc2,
                                              const float* __restrict__ Wc3,
                                              unsigned short* __restrict__ Wt1,
                                              unsigned short* __restrict__ Wt2,
                                              unsigned short* __restrict__ Wt3,
                                              int* __restrict__ bcur,
                                              const int* __restrict__ batch,
                                              int* __restrict__ gstart,
                                              unsigned short* __restrict__ hba,
                                              unsigned short* __restrict__ hbb,
                                              unsigned char* __restrict__ h8,
                                              unsigned short* __restrict__ hmb,
                                              float* __restrict__ gout,
                                              const float* __restrict__ x,
                                              const float* __restrict__ W,
                                              const float* __restrict__ b,
                                              const float* __restrict__ gamma,
                                              const float* __restrict__ beta) {
  const int bid = blockIdx.x;
  const int t = threadIdx.x;
  if (bid < 384) {
    const float* Wc = (bid < 128) ? Wc1 : (bid < 256) ? Wc2 : Wc3;
    unsigned short* Wt = (bid < 128) ? Wt1 : (bid < 256) ? Wt2 : Wt3;
    int idx = (bid & 127) * 256 + t;  // 0..32767
    int k = idx >> 7;
    int n = idx & 127;
    Wt[n * 256 + k] = f2b(Wc[k * DD + n]);
    return;
  }
  if (bid == 384) {
    if (t < NB) bcur[t] = t * MAXBE;
    if (t >= 128 && t <= 128 + NG) {
      int g = t - 128;
      int lo = 0, hi = NN;
      while (lo < hi) {
        int mid = (lo + hi) >> 1;
        if (batch[mid] < g) lo = mid + 1; else hi = mid;
      }
      gstart[g] = lo;
    }
    return;
  }
  if (bid == 385) {  // zero pad rows of hba/hbb/hmb (u32 views) and h8
    unsigned int* pa = reinterpret_cast<unsigned int*>(hba + (size_t)NN * DD);
    unsigned int* pb = reinterpret_cast<unsigned int*>(hbb + (size_t)NN * DD);
    unsigned int* pm = reinterpret_cast<unsigned int*>(hmb + (size_t)NN * DD);
    unsigned int* p8 = reinterpret_cast<unsigned int*>(h8 + (size_t)NN * DD);
    const int n2 = (NNP - NN) * DD / 2;   // u32 count for bf16 buffers
    for (int i = t; i < n2; i += 256) { pa[i] = 0; pb[i] = 0; pm[i] = 0; }
    for (int i = t; i < (NNP - NN) * DD / 4; i += 256) p8[i] = 0;
    return;
  }
  if (bid == 386) {  // zero graph output (atomic pool accumulates into it)
    for (int i = t; i < NG * 256; i += 256) gout[i] = 0.f;
    return;
  }
  // ---- embed: relu(LN(x@W+b)) -> bf16 + fp8
  const int wid = t >> 6;
  const int lane = t & 63;
  const int node = (bid - EMB0) * 4 + wid;
  if (node >= NN) return;
  float xr[FIN];
#pragma unroll
  for (int k = 0; k < FIN; ++k) xr[k] = x[node * FIN + k];
  const int c0 = lane, c1 = lane + 64;
  float a0 = b[c0], a1 = b[c1];
#pragma unroll
  for (int k = 0; k < FIN; ++k) {
    a0 += xr[k] * W[k * DD + c0];
    a1 += xr[k] * W[k * DD + c1];
  }
  float s = a0 + a1;
#pragma unroll
  for (int m = 1; m < 64; m <<= 1) s += __shfl_xor(s, m, 64);
  float mean = s * (1.f / DD);
  float d0 = a0 - mean, d1 = a1 - mean;
  float v = d0 * d0 + d1 * d1;
#pragma unroll
  for (int m = 1; m < 64; m <<= 1) v += __shfl_xor(v, m, 64);
  float r = rsqrtf(v * (1.f / DD) + LN_EPS);
  float o0 = fmaxf(d0 * r * gamma[c0] + beta[c0], 0.f);
  float o1 = fmaxf(d1 * r * gamma[c1] + beta[c1], 0.f);
  hba[(size_t)node * DD + c0] = f2b(o0);
  hba[(size_t)node * DD + c1] = f2b(o1);
  h8[(size_t)node * DD + c0] = f2e4m3(o0);
  h8[(size_t)node * DD + c1] = f2e4m3(o1);
}

// ---------------------------------------------------------------- binned scatter (fixed regions)
__global__ __launch_bounds__(512) void k_bscatter(const int* __restrict__ src,
                                                  const int* __restrict__ dst,
                                                  int* __restrict__ bcur,
                                                  unsigned int* __restrict__ bents) {
  __shared__ int lh[NB], lbase[NB], gbase[NB], lcnt[NB];
  __shared__ int stmp[256];
  __shared__ unsigned int sbuf[CH];
  const int t = threadIdx.x;
  const int e0 = blockIdx.x * CH;
  const int n = min(CH, NE - e0);

  for (int i = t; i < NB; i += 512) { lh[i] = 0; lcnt[i] = 0; }
  __syncthreads();

  unsigned int ent[16];
  int eb[16];
#pragma unroll
  for (int k = 0; k < 16; ++k) {
    int i = k * 512 + t;
    if (i < n) {
      int s = src[e0 + i], d = dst[e0 + i];
      ent[k] = ((unsigned)d << 16) | (unsigned)s;  // both < 65536
      eb[k] = d >> BSHIFT;
      atomicAdd(&lh[eb[k]], 1);
    } else {
      eb[k] = -1;
    }
  }
  __syncthreads();
  if (t < 256) stmp[t] = (t < NB) ? lh[t] : 0;
  __syncthreads();
  for (int off = 1; off < 256; off <<= 1) {
    int v = 0;
    if (t < 256 && t >= off) v = stmp[t - off];
    __syncthreads();
    if (t < 256) stmp[t] += v;
    __syncthreads();
  }
  if (t < NB) lbase[t] = (t == 0) ? 0 : stmp[t - 1];
  __syncthreads();
  if (t < NB && lh[t] > 0) gbase[t] = atomicAdd(&bcur[t], lh[t]);
  __syncthreads();
#pragma unroll
  for (int k = 0; k < 16; ++k) {
    if (eb[k] >= 0) {
      int r = atomicAdd(&lcnt[eb[k]], 1);
      sbuf[lbase[eb[k]] + r] = ent[k];
    }
  }
  __syncthreads();
  for (int i = t; i < n; i += 512) {
    unsigned int e = sbuf[i];
    int b = e >> 24;
    int pos = gbase[b] + (i - lbase[b]);
    if (pos < (b + 1) * MAXBE) bents[pos] = e;  // overflow guard (statistically never)
  }
}

// ---------------------------------------------------------------- per-bucket counting sort
__global__ __launch_bounds__(512) void k_sort(const unsigned int* __restrict__ bents,
                                              const int* __restrict__ bcur,
                                              int* __restrict__ prowptr,
                                              int* __restrict__ degv,
                                              unsigned short* __restrict__ csr16) {
  __shared__ int lh[256], lsc[256], plsc[256], lc2[256];
  const int b = blockIdx.x, t = threadIdx.x;
  const int base = b * MAXBE;
  const int nb = min(bcur[b] - base, MAXBE);
  const int pbase = b * MAXPB;

  if (t < 256) { lh[t] = 0; lc2[t] = 0; }
  __syncthreads();
  for (int i = t; i < nb; i += 512)
    atomicAdd(&lh[(bents[base + i] >> 16) & 255], 1);
  __syncthreads();
  if (t < 256) { lsc[t] = lh[t]; plsc[t] = (lh[t] + 31) & ~31; }
  __syncthreads();
  for (int off = 1; off < 256; off <<= 1) {
    int v = 0, pv = 0;
    if (t < 256 && t >= off) { v = lsc[t - off]; pv = plsc[t - off]; }
    __syncthreads();
    if (t < 256) { lsc[t] += v; plsc[t] += pv; }
    __syncthreads();
  }
  int ex = 0, pex = 0;
  if (t < 256) { ex = (t == 0) ? 0 : lsc[t - 1]; pex = (t == 0) ? 0 : plsc[t - 1]; }
  __syncthreads();
  if (t < 256) {
    lsc[t] = ex;
    plsc[t] = pex;
    int gnode = b * 256 + t;
    if (gnode < NN) { prowptr[gnode] = pbase + pex; degv[gnode] = lh[t]; }
  }
  __syncthreads();
  for (int i = t; i < nb; i += 512) {
    unsigned int e = bents[base + i];
    int dl = (e >> 16) & 255;
    int r = atomicAdd(&lc2[dl], 1);
    csr16[pbase + plsc[dl] + r] = (unsigned short)(e & 0xFFFF);
  }
  __syncthreads();
  if (t < 256) {
    int d = lh[t];
    int pd = (d + 31) & ~31;
    int o = pbase + plsc[t];
    for (int k = d; k < pd; ++k) csr16[o + k] = (unsigned short)NN;  // sentinel -> zero row
  }
}

// ---------------------------------------------------------------- scatter-mean (fp8 gather, v2)
// one WAVE per node; dword loads: half-wave per row of each pair (4 fp8 ch / lane),
// shfl_xor(32) combine -> halves VMEM instruction count vs u16 loads.
__global__ __launch_bounds__(256) void k_aggr(const unsigned char* __restrict__ h8,
                                              const int* __restrict__ prowptr,
                                              const int* __restrict__ degv,
                                              const unsigned short* __restrict__ csr16,
                                              unsigned short* __restrict__ hmb) {
  const int wid = __builtin_amdgcn_readfirstlane(threadIdx.x >> 6);
  const int l = threadIdx.x & 63;
  const int lh = l & 31;     // channel-quad id (channels 4*lh .. 4*lh+3)
  const int hi = l >> 5;     // 0: low row of pair, 1: high row
  const int node = blockIdx.x * 4 + wid;   // grid covers exactly NN
  const int pbeg = __builtin_amdgcn_readfirstlane(prowptr[node]);
  const int deg = __builtin_amdgcn_readfirstlane(degv[node]);
  const int nch = (deg + 31) >> 5;
  const unsigned int* __restrict__ cp =
      reinterpret_cast<const unsigned int*>(csr16 + pbeg);  // uniform -> scalar loads
  float a0 = 0.f, a1 = 0.f, a2 = 0.f, a3 = 0.f;
  for (int c = 0; c < nch; ++c) {
#pragma unroll
    for (int q = 0; q < 16; ++q) {
      unsigned int pair = cp[c * 16 + q];
      int row = hi ? (int)(pair >> 16) : (int)(pair & 0xFFFFu);
      const unsigned int* rp =
          reinterpret_cast<const unsigned int*>(h8 + (size_t)row * DD);
      unsigned int u = rp[lh];                              // 4 fp8 channels
      f32x2 dlo = __builtin_amdgcn_cvt_pk_f32_fp8((int)u, false);
      f32x2 dhi = __builtin_amdgcn_cvt_pk_f32_fp8((int)u, true);
      a0 += dlo.x; a1 += dlo.y; a2 += dhi.x; a3 += dhi.y;
    }
  }
  // combine the two half-waves (complementary rows, same channels)
  a0 += __shfl_xor(a0, 32, 64);
  a1 += __shfl_xor(a1, 32, 64);
  a2 += __shfl_xor(a2, 32, 64);
  a3 += __shfl_xor(a3, 32, 64);
  if (hi == 0) {
    float inv = 1.f / (float)max(deg, 1);
    ushort4 o;
    o.x = f2b(a0 * inv); o.y = f2b(a1 * inv);
    o.z = f2b(a2 * inv); o.w = f2b(a3 * inv);
    reinterpret_cast<ushort4*>(hmb + (size_t)node * DD)[lh] = o;
  }
}

// ---------------------------------------------------------------- MFMA linear(256->128)+LN+ReLU
// (round-11 LDS-staged version, unchanged)
template <int OUT_BF16>
__global__ __launch_bounds__(512, 4) void k_lin_mfma(const unsigned short* __restrict__ hb,
                                                     const unsigned short* __restrict__ hmb,
                                                     const unsigned short* __restrict__ Wt,
                                                     const float* __restrict__ bias,
                                                     const float* __restrict__ gamma,
                                                     const float* __restrict__ beta,
                                                     void* __restrict__ outv,
                                                     unsigned char* __restrict__ h8out) {
  __shared__ unsigned short wlds[128 * 256];  // 64 KB, granule-swizzled rows
  __shared__ float sred[4][16][2][2];         // [group][node16][half][{s,q}]
  const int tid = threadIdx.x;
  const int w = tid >> 6;
  const int l = tid & 63;
  const int g = w & 3;          // node group (16 nodes)
  const int hh = w >> 2;        // channel half: t = hh*4 + t2
  const int c16 = l & 15;
  const int kg = l >> 4;
  const int node = blockIdx.x * 64 + g * 16 + c16;

  // ---- stage W^T -> LDS (coalesced 16B loads; swizzled 16B-granule writes)
#pragma unroll
  for (int it = 0; it < 8; ++it) {
    int idx = it * 512 + tid;      // granule id 0..4095
    int r = idx >> 5;              // row 0..127
    int gr = idx & 31;             // granule within row
    uint4 v = *reinterpret_cast<const uint4*>(Wt + (size_t)r * 256 + gr * 8);
    int gs = gr ^ (r & 7);
    *reinterpret_cast<uint4*>(wlds + (size_t)r * 256 + gs * 8) = v;
  }

  // ---- B-frags (global, 8 x 16B per lane) overlap with staging
  const unsigned short* brow_self = hb + (size_t)node * DD + kg * 8;
  const unsigned short* brow_mean = hmb + (size_t)node * DD + kg * 8;
  bf16x8 bfr[8];
#pragma unroll
  for (int kc = 0; kc < 4; ++kc)
    bfr[kc] = *reinterpret_cast<const bf16x8*>(brow_self + kc * 32);
#pragma unroll
  for (int kc = 0; kc < 4; ++kc)
    bfr[4 + kc] = *reinterpret_cast<const bf16x8*>(brow_mean + kc * 32);

  __syncthreads();

  f32x4 acc[4];
#pragma unroll
  for (int t2 = 0; t2 < 4; ++t2) acc[t2] = (f32x4){0.f, 0.f, 0.f, 0.f};

#pragma unroll
  for (int t2 = 0; t2 < 4; ++t2) {
    const int row = (hh * 4 + t2) * 16 + c16;
    const unsigned short* wr = wlds + (size_t)row * 256;
    const int sw = c16 & 7;
#pragma unroll
    for (int kc = 0; kc < 8; ++kc) {
      bf16x8 a = *reinterpret_cast<const bf16x8*>(wr + ((kc * 4 + kg) ^ sw) * 8);
      acc[t2] = __builtin_amdgcn_mfma_f32_16x16x32_bf16(a, bfr[kc], acc[t2], 0, 0, 0);
    }
  }

  // bias add: channel = (hh*4+t2)*16 + kg*4 + i
#pragma unroll
  for (int t2 = 0; t2 < 4; ++t2) {
    float4 bv = reinterpret_cast<const float4*>(bias)[(hh * 4 + t2) * 4 + kg];
    acc[t2][0] += bv.x; acc[t2][1] += bv.y; acc[t2][2] += bv.z; acc[t2][3] += bv.w;
  }

  // LN partials for this half (64 channels): s = sum, q = sumsq
  float s = 0.f, q = 0.f;
#pragma unroll
  for (int t2 = 0; t2 < 4; ++t2)
#pragma unroll
    for (int i = 0; i < 4; ++i) { float v = acc[t2][i]; s += v; q += v * v; }
#pragma unroll
  for (int m = 16; m < 64; m <<= 1) {
    s += __shfl_xor(s, m, 64);
    q += __shfl_xor(q, m, 64);
  }
  if (kg == 0) { sred[g][c16][hh][0] = s; sred[g][c16][hh][1] = q; }
  __syncthreads();
  float st = sred[g][c16][0][0] + sred[g][c16][1][0];
  float qt = sred[g][c16][0][1] + sred[g][c16][1][1];
  float mean = st * (1.f / DD);
  float var = fmaxf(qt * (1.f / DD) - mean * mean, 0.f);
  float r = rsqrtf(var + LN_EPS);

  if (node < NN) {
#pragma unroll
    for (int t2 = 0; t2 < 4; ++t2) {
      int cbase = (hh * 4 + t2) * 16 + kg * 4;
      float4 gv = reinterpret_cast<const float4*>(gamma)[cbase >> 2];
      float4 btv = reinterpret_cast<const float4*>(beta)[cbase >> 2];
      float v0 = fmaxf((acc[t2][0] - mean) * r * gv.x + btv.x, 0.f);
      float v1 = fmaxf((acc[t2][1] - mean) * r * gv.y + btv.y, 0.f);
      float v2 = fmaxf((acc[t2][2] - mean) * r * gv.z + btv.z, 0.f);
      float v3 = fmaxf((acc[t2][3] - mean) * r * gv.w + btv.w, 0.f);
      if (OUT_BF16) {
        ushort4 ob;
        ob.x = f2b(v0); ob.y = f2b(v1); ob.z = f2b(v2); ob.w = f2b(v3);
        *reinterpret_cast<ushort4*>((unsigned short*)outv + (size_t)node * DD + cbase) = ob;
        int p8 = __builtin_amdgcn_cvt_pk_fp8_f32(v0, v1, 0, false);
        p8 = __builtin_amdgcn_cvt_pk_fp8_f32(v2, v3, p8, true);
        *reinterpret_cast<unsigned int*>(h8out + (size_t)node * DD + cbase) = (unsigned int)p8;
      } else {
        float4 of = make_float4(v0, v1, v2, v3);
        *reinterpret_cast<float4*>((float*)outv + (size_t)node * DD + cbase) = of;
      }
    }
  }
}

// ---------------------------------------------------------------- graph pooling (single pass,
// atomic): post-ReLU values >= 0 so max identity is 0 and int-bits atomicMax is valid;
// mean = atomicAdd of pre-divided partials. gout zeroed in k_prep.
__global__ __launch_bounds__(128) void k_pool(const float* __restrict__ ne,
                                              const int* __restrict__ gstart,
                                              float* __restrict__ gout) {
  const int g = blockIdx.x / PSEG;
  const int sg = blockIdx.x % PSEG;
  const int c = threadIdx.x;
  const int beg = gstart[g], end = gstart[g + 1];
  const int len = end - beg;
  const int per = (len + PSEG - 1) / PSEG;
  const int n0 = beg + sg * per;
  const int n1 = min(n0 + per, end);
  float s = 0.f, mx = 0.f;
  for (int n = n0; n < n1; ++n) {
    float v = ne[(size_t)n * DD + c];
    s += v;
    mx = fmaxf(mx, v);
  }
  atomicAdd(&gout[(size_t)g * 256 + c], s / (float)max(len, 1));
  atomicMax(reinterpret_cast<int*>(&gout[(size_t)g * 256 + 128 + c]), __float_as_int(mx));
}

// ---------------------------------------------------------------- launch
static inline size_t align_up(size_t v, size_t a) { return (v + a - 1) & ~(a - 1); }

extern "C" void kernel_launch(void* const* d_in, const int* in_sizes, int n_in,
                              void* d_out, int out_size, void* d_ws, size_t ws_size,
                              hipStream_t stream) {
  const float* x     = (const float*)d_in[0];
  const int*   ei    = (const int*)d_in[1];
  const int*   batch = (const int*)d_in[2];
  const float* W_emb = (const float*)d_in[3];
  const float* b_emb = (const float*)d_in[4];
  const float* g0    = (const float*)d_in[5];
  const float* bt0   = (const float*)d_in[6];
  const float* Wc1   = (const float*)d_in[7];
  const float* bc1   = (const float*)d_in[8];
  const float* g1    = (const float*)d_in[9];
  const float* bt1   = (const float*)d_in[10];
  const float* Wc2   = (const float*)d_in[11];
  const float* bc2   = (const float*)d_in[12];
  const float* g2    = (const float*)d_in[13];
  const float* bt2   = (const float*)d_in[14];
  const float* Wc3   = (const float*)d_in[15];
  const float* bc3   = (const float*)d_in[16];
  const float* g3    = (const float*)d_in[17];
  const float* bt3   = (const float*)d_in[18];

  const int* src = ei;
  const int* dst = ei + NE;

  float* out_node  = (float*)d_out;                     // N*D fp32
  float* out_graph = (float*)d_out + (size_t)NN * DD;   // G*256 fp32

  char* p = (char*)d_ws;
  auto alloc = [&](size_t bytes) { char* r = p; p += align_up(bytes, 256); return r; };
  int*            prowptr = (int*)alloc((size_t)NN * sizeof(int));
  int*            degv    = (int*)alloc((size_t)NN * sizeof(int));
  int*            bcur    = (int*)alloc(NB * sizeof(int));
  int*            gstart  = (int*)alloc((NG + 1) * sizeof(int));
  unsigned int*   bents   = (unsigned int*)alloc((size_t)NB * MAXBE * 4);
  unsigned short* csr16   = (unsigned short*)alloc((size_t)NB * MAXPB * 2);
  unsigned short* hba     = (unsigned short*)alloc((size_t)NNP * DD * 2);
  unsigned short* hbb     = (unsigned short*)alloc((size_t)NNP * DD * 2);
  unsigned char*  h8      = (unsigned char*)alloc((size_t)NNP * DD);
  unsigned short* hmb     = (unsigned short*)alloc((size_t)NNP * DD * 2);
  unsigned short* Wt1     = (unsigned short*)alloc(128 * 256 * 2);
  unsigned short* Wt2     = (unsigned short*)alloc(128 * 256 * 2);
  unsigned short* Wt3     = (unsigned short*)alloc(128 * 256 * 2);

  // prep (+embed): Wt x3, bcur, gstart, pads, gout zero, node embed  (1 dispatch)
  k_prep<<<EMB0 + NN / 4, 256, 0, stream>>>(Wc1, Wc2, Wc3, Wt1, Wt2, Wt3, bcur, batch,
                                            gstart, hba, hbb, h8, hmb, out_graph,
                                            x, W_emb, b_emb, g0, bt0);
  // CSR build (2 dispatches)
  k_bscatter<<<(NE + CH - 1) / CH, 512, 0, stream>>>(src, dst, bcur, bents);
  k_sort<<<NB, 512, 0, stream>>>(bents, bcur, prowptr, degv, csr16);

  const int LIN_GRID = NNP / 64;   // 782
  const int AGGR_GRID = NN / 4;    // 12500 (wave per node)
  // layer 1
  k_aggr<<<AGGR_GRID, 256, 0, stream>>>(h8, prowptr, degv, csr16, hmb);
  k_lin_mfma<1><<<LIN_GRID, 512, 0, stream>>>(hba, hmb, Wt1, bc1, g1, bt1, hbb, h8);
  // layer 2
  k_aggr<<<AGGR_GRID, 256, 0, stream>>>(h8, prowptr, degv, csr16, hmb);
  k_lin_mfma<1><<<LIN_GRID, 512, 0, stream>>>(hbb, hmb, Wt2, bc2, g2, bt2, hba, h8);
  // layer 3
  k_aggr<<<AGGR_GRID, 256, 0, stream>>>(h8, prowptr, degv, csr16, hmb);
  k_lin_mfma<0><<<LIN_GRID, 512, 0, stream>>>(hba, hmb, Wt3, bc3, g3, bt3, out_node, h8);

  // pooling (1 dispatch, atomic)
  k_pool<<<NG * PSEG, 128, 0, stream>>>(out_node, gstart, out_graph);
}